// Round 13
// baseline (294.777 us; speedup 1.0000x reference)
//
#include <hip/hip_runtime.h>
#include <hip/hip_fp16.h>
#include <math.h>

// ---------------------------------------------------------------------------
// EquivariantNet forward — round 13.
// r12 (best, 291.9 us) with k_attn/k_out re-parallelized: 32 lanes per node
// (2 nodes/wave, 8 nodes/block -> 2x waves, half per-lane serial work in the
// alpha-v accumulation). Conv untouched (r12 body, ~45 us plateau).
// Shapes: N=8192, E=131072, C=16, mid=16, KV=16, ckv=8, Co=8, HEADS=4, L=2
// ---------------------------------------------------------------------------

typedef _Float16 half8 __attribute__((ext_vector_type(8)));
typedef float f32x4 __attribute__((ext_vector_type(4)));

union AF {
    half8 h8;
    __half2 h2[4];
};
union U32h2 {
    unsigned u;
    __half2 h;
};

static __device__ __forceinline__ float h2f_lo(unsigned u) {
    U32h2 w; w.u = u; return __low2float(w.h);
}
static __device__ __forceinline__ float h2f_hi(unsigned u) {
    U32h2 w; w.u = u; return __high2float(w.h);
}

// ---------------- CSR build over edge_dst ----------------
__global__ void k_hist(const int* __restrict__ dst, int* __restrict__ counts, int E) {
    int e = blockIdx.x * 256 + threadIdx.x;
    if (e < E) atomicAdd(&counts[dst[e]], 1);
}

__global__ __launch_bounds__(1024) void k_scan(const int* __restrict__ counts,
                                               int* __restrict__ rowptr,
                                               int* __restrict__ cursor,
                                               int N, int CH) {
    __shared__ int part[1024];
    int t = threadIdx.x;
    int s = 0;
    for (int i = 0; i < CH; ++i) {
        int idx = t * CH + i;
        if (idx < N) s += counts[idx];
    }
    part[t] = s;
    __syncthreads();
    for (int off = 1; off < 1024; off <<= 1) {
        int v = (t >= off) ? part[t - off] : 0;
        __syncthreads();
        part[t] += v;
        __syncthreads();
    }
    int run = (t == 0) ? 0 : part[t - 1];
    for (int i = 0; i < CH; ++i) {
        int idx = t * CH + i;
        if (idx < N) {
            rowptr[idx] = run;
            cursor[idx] = run;
            run += counts[idx];
        }
    }
    if (t == 0) rowptr[N] = part[1023];
}

__global__ void k_scatter(const int* __restrict__ dst, int* __restrict__ cursor,
                          int* __restrict__ pose, int E) {
    int e = blockIdx.x * 256 + threadIdx.x;
    if (e < E) {
        int pos = atomicAdd(&cursor[dst[e]], 1);
        pose[e] = pos;
    }
}

// ---------------- fused init: W-frag permute + ef->f16 + layer0 q + b11h ----
__global__ void k_init(const float* __restrict__ x0, const float* __restrict__ x1,
                       const float* __restrict__ ef, const float* __restrict__ b11,
                       const float* __restrict__ kvw1, const float* __restrict__ fcw1,
                       const float* __restrict__ kvw2n, const float* __restrict__ kvw211,
                       const float* __restrict__ fcw2n, const float* __restrict__ fcw211,
                       const float* __restrict__ wq,
                       unsigned short* __restrict__ efh,
                       unsigned short* __restrict__ Wfrag,
                       float* __restrict__ q0, float* __restrict__ q1,
                       unsigned short* __restrict__ b11h,
                       int N, int E) {
    int i = blockIdx.x * 256 + threadIdx.x;
    if (i < 156 * 64 * 8) {
        int t = i;
        int j = t & 7;
        int lane = (t >> 3) & 63;
        int row = t >> 9;
        int quad = lane >> 4, m = lane & 15;
        int c = row / 52, r = row % 52;
        int KVO = (c < 2) ? 16 : 8;
        const float* w1src = (c < 2) ? (kvw1 + c * 1024) : fcw1;
        const float* w2n = (c < 2) ? (kvw2n + c * 12288) : fcw2n;
        const float* w211 = (c < 2) ? (kvw211 + c * 12288) : fcw211;
        float v = 0.f;
        if (r < 4) {
            if (quad < 2) v = w1src[r * 256 + (quad * 8 + j) * 16 + m];
        } else if (r < 28) {
            int fam = (r - 4) >> 3, kk = (r - 4) & 7;
            int h = quad * 4 + ((j >> 1) & 3), ii = 2 * kk + (j & 1);
            if (m < KVO) v = w2n[((fam * 16 + h) * KVO + m) * 16 + ii];
        } else {
            int kk2 = r - 28;
            int h = quad * 4 + ((j >> 1) & 3);
            int ifx = 2 * kk2 + (j & 1);
            int ii = ifx / 3, f = ifx % 3;
            if (m < KVO) v = w211[((h * KVO + m) * 16 + ii) * 3 + f];
        }
        Wfrag[t] = __half_as_ushort(__float2half(v));
        return;
    }
    i -= 156 * 64 * 8;
    if (i < E * 16) { efh[i] = __half_as_ushort(__float2half(ef[i])); return; }
    i -= E * 16;
    if (i < N * 32) {
        int n = i >> 5, comp = i & 31;
        if (comp < 8) {
            float a = 0.f;
#pragma unroll
            for (int c = 0; c < 16; ++c) a += x0[n * 16 + c] * wq[c * 8 + comp];
            q0[n * 8 + comp] = a;
        } else {
            int idx = comp - 8, dd = idx / 3, mm = idx % 3;
            float a = 0.f;
#pragma unroll
            for (int c = 0; c < 16; ++c) a += x1[n * 48 + c * 3 + mm] * wq[128 + c * 8 + dd];
            q1[n * 24 + dd * 3 + mm] = a;
        }
        return;
    }
    i -= N * 32;
    if (i < E * 27) {
        int e = i / 27, k = i - e * 27;
        b11h[(size_t)e * 28 + k] = __half_as_ushort(__float2half(b11[i]));
    }
}

// ---------------- fused MFMA conv (+H, +z), f16 (r12 body) ----------------
template <int KVO, bool DO_Z>
__global__ __launch_bounds__(256) void k_conv(
    int E,
    const int* __restrict__ src, const int* __restrict__ dst,
    const int* __restrict__ pose,
    const float* __restrict__ xs0, const float* __restrict__ xs1,
    const float* __restrict__ b00, const float* __restrict__ b01,
    const float* __restrict__ b10,
    const unsigned short* __restrict__ b11h,   // (E,28) f16
    const unsigned short* __restrict__ efh,    // (E,16) f16
    const unsigned short* __restrict__ Wfrag,  // frag-ordered weights (f16)
    int wbase,
    const float* __restrict__ q0, const float* __restrict__ q1,
    float* __restrict__ vrow, float* __restrict__ zb)
{
    __shared__ __align__(16) unsigned xBL[4][16 * 74];
    int tid = threadIdx.x;
    int wave = tid >> 6, lane = tid & 63;
    int tile = blockIdx.x * 4 + wave;
    if (tile * 16 >= E) return;
    int m = lane & 15, quad = lane >> 4;
    int e0 = tile * 16;
    int me = e0 + m;
    int s = src[me];
    unsigned* xw = xBL[wave];
    const half8* W8 = (const half8*)Wfrag;

    // ---- xB[p][if] = sum_q x1[i][q]*b11[p][q][f]; quad covers if [quad*12,+12) ----
    {
        float x1c[12];
        const float4* xp = (const float4*)(xs1 + (size_t)s * 48 + quad * 12);
#pragma unroll
        for (int cc = 0; cc < 3; ++cc) {
            float4 v = xp[cc];
            x1c[cc * 4 + 0] = v.x; x1c[cc * 4 + 1] = v.y;
            x1c[cc * 4 + 2] = v.z; x1c[cc * 4 + 3] = v.w;
        }
        float b11r[27];
        {
            const uint2* bp = (const uint2*)(b11h + (size_t)me * 28);
#pragma unroll
            for (int t = 0; t < 6; ++t) {
                uint2 uu = bp[t];
                b11r[4 * t + 0] = h2f_lo(uu.x);
                b11r[4 * t + 1] = h2f_hi(uu.x);
                b11r[4 * t + 2] = h2f_lo(uu.y);
                b11r[4 * t + 3] = h2f_hi(uu.y);
            }
            uint2 uu = bp[6];
            b11r[24] = h2f_lo(uu.x);
            b11r[25] = h2f_hi(uu.x);
            b11r[26] = h2f_lo(uu.y);
        }
#pragma unroll
        for (int p = 0; p < 3; ++p) {
            float vals[12];
#pragma unroll
            for (int i2 = 0; i2 < 4; ++i2) {
#pragma unroll
                for (int f = 0; f < 3; ++f) {
                    float a = 0.f;
#pragma unroll
                    for (int q = 0; q < 3; ++q) a += x1c[i2 * 3 + q] * b11r[p * 9 + q * 3 + f];
                    vals[i2 * 3 + f] = a;
                }
            }
            unsigned uu[6];
#pragma unroll
            for (int u = 0; u < 6; ++u) {
                U32h2 w;
                w.h = __float22half2_rn(make_float2(vals[2 * u], vals[2 * u + 1]));
                uu[u] = w.u;
            }
            int boff = m * 74 + p * 24 + quad * 6;
            *(uint2*)&xw[boff + 0] = make_uint2(uu[0], uu[1]);
            *(uint2*)&xw[boff + 2] = make_uint2(uu[2], uu[3]);
            *(uint2*)&xw[boff + 4] = make_uint2(uu[4], uu[5]);
        }
    }
    __syncthreads();

    // ---- x0 / t10 rows as natural half2 pairs ----
    __half2 x0p[8], t10p[8];
    {
        const float4* p = (const float4*)(xs0 + (size_t)s * 16);
#pragma unroll
        for (int k = 0; k < 4; ++k) {
            float4 v = p[k];
            x0p[2 * k + 0] = __float22half2_rn(make_float2(v.x, v.y));
            x0p[2 * k + 1] = __float22half2_rn(make_float2(v.z, v.w));
        }
        float bq0 = b10[(size_t)me * 3 + 0], bq1 = b10[(size_t)me * 3 + 1],
              bq2 = b10[(size_t)me * 3 + 2];
        const float4* xp = (const float4*)(xs1 + (size_t)s * 48);
        float tf[16];
#pragma unroll
        for (int g = 0; g < 4; ++g) {
            float4 a = xp[g * 3 + 0], b = xp[g * 3 + 1], cc = xp[g * 3 + 2];
            float xf[12] = {a.x, a.y, a.z, a.w, b.x, b.y, b.z, b.w, cc.x, cc.y, cc.z, cc.w};
#pragma unroll
            for (int i2 = 0; i2 < 4; ++i2)
                tf[g * 4 + i2] = bq0 * xf[i2 * 3] + bq1 * xf[i2 * 3 + 1] + bq2 * xf[i2 * 3 + 2];
        }
#pragma unroll
        for (int k = 0; k < 8; ++k)
            t10p[k] = __float22half2_rn(make_float2(tf[2 * k], tf[2 * k + 1]));
    }

    // ---- H via 4 f16 MFMAs ----
    __half2 Hd[4][4];
    {
        half8 efr = {0, 0, 0, 0, 0, 0, 0, 0};
        if (quad < 2) efr = *(const half8*)(efh + (size_t)me * 16 + quad * 8);
        f32x4 z4 = {0.f, 0.f, 0.f, 0.f};
#pragma unroll
        for (int pp = 0; pp < 4; ++pp) {
            half8 w1f = W8[(size_t)(wbase + pp) * 64 + lane];
            f32x4 hacc = __builtin_amdgcn_mfma_f32_16x16x32_f16(w1f, efr, z4, 0, 0, 0);
#pragma unroll
            for (int r = 0; r < 4; ++r)
                Hd[pp][r] = __float2half2_rn(__float2half(fmaxf(hacc[r], 0.f)));
        }
    }

    f32x4 acc0 = {0.f, 0.f, 0.f, 0.f}, acc1 = acc0, acc2 = acc0;
    f32x4 accP0 = acc0, accP1 = acc0, accP2 = acc0;

    // ---- loop1: fams 0,1,2 (K=256) ----
#pragma unroll
    for (int kk = 0; kk < 8; ++kk) {
        __half2 xp_ = x0p[kk], tp_ = t10p[kk];
        AF a0, a1, a2;
#pragma unroll
        for (int t = 0; t < 4; ++t) {
            a0.h2[t] = __hmul2(Hd[0][t], xp_);
            a1.h2[t] = __hmul2(Hd[1][t], xp_);
            a2.h2[t] = __hmul2(Hd[2][t], tp_);
        }
        half8 w0 = W8[(size_t)(wbase + 4 + kk) * 64 + lane];
        half8 w1f = W8[(size_t)(wbase + 12 + kk) * 64 + lane];
        half8 w2f = W8[(size_t)(wbase + 20 + kk) * 64 + lane];
        acc0 = __builtin_amdgcn_mfma_f32_16x16x32_f16(w0, a0.h8, acc0, 0, 0, 0);
        acc1 = __builtin_amdgcn_mfma_f32_16x16x32_f16(w1f, a1.h8, acc1, 0, 0, 0);
        acc2 = __builtin_amdgcn_mfma_f32_16x16x32_f16(w2f, a2.h8, acc2, 0, 0, 0);
    }

    // ---- loop2: fam3 (K=768) ----
#pragma unroll
    for (int kko = 0; kko < 12; ++kko) {
        uint2 xu0 = *(const uint2*)&xw[m * 74 + 0 * 24 + 2 * kko];
        uint2 xu1 = *(const uint2*)&xw[m * 74 + 1 * 24 + 2 * kko];
        uint2 xu2 = *(const uint2*)&xw[m * 74 + 2 * 24 + 2 * kko];
        unsigned pv0[2] = {xu0.x, xu0.y};
        unsigned pv1[2] = {xu1.x, xu1.y};
        unsigned pv2[2] = {xu2.x, xu2.y};
#pragma unroll
        for (int t = 0; t < 2; ++t) {
            U32h2 u0, u1, u2;
            u0.u = pv0[t]; u1.u = pv1[t]; u2.u = pv2[t];
            AF a0, a1, a2;
#pragma unroll
            for (int r = 0; r < 4; ++r) {
                a0.h2[r] = __hmul2(Hd[3][r], u0.h);
                a1.h2[r] = __hmul2(Hd[3][r], u1.h);
                a2.h2[r] = __hmul2(Hd[3][r], u2.h);
            }
            half8 wf = W8[(size_t)(wbase + 28 + 2 * kko + t) * 64 + lane];
            accP0 = __builtin_amdgcn_mfma_f32_16x16x32_f16(wf, a0.h8, accP0, 0, 0, 0);
            accP1 = __builtin_amdgcn_mfma_f32_16x16x32_f16(wf, a1.h8, accP1, 0, 0, 0);
            accP2 = __builtin_amdgcn_mfma_f32_16x16x32_f16(wf, a2.h8, accP2, 0, 0, 0);
        }
    }

    // ---- epilogue (b's fp32) ----
    float b00r = b00[me];
    float b01r0 = b01[(size_t)me * 3 + 0], b01r1 = b01[(size_t)me * 3 + 1],
          b01r2 = b01[(size_t)me * 3 + 2];
    float o0v[4], o1v[4][3];
#pragma unroll
    for (int r = 0; r < 4; ++r) {
        o0v[r] = b00r * acc0[r] + acc2[r];
        o1v[r][0] = b01r0 * acc1[r] + accP0[r];
        o1v[r][1] = b01r1 * acc1[r] + accP1[r];
        o1v[r][2] = b01r2 * acc1[r] + accP2[r];
    }
    int pos = pose[me];
    bool doStore = DO_Z ? (quad >= 2) : (quad < 2);
    if (doStore) {
        int qa = DO_Z ? (quad - 2) : quad;
        float* vp = vrow + (size_t)pos * 32;
        *(float4*)&vp[qa * 4] = make_float4(o0v[0], o0v[1], o0v[2], o0v[3]);
        float* p1 = vp + 8 + qa * 12;
        *(float4*)&p1[0] = make_float4(o1v[0][0], o1v[0][1], o1v[0][2], o1v[1][0]);
        *(float4*)&p1[4] = make_float4(o1v[1][1], o1v[1][2], o1v[2][0], o1v[2][1]);
        *(float4*)&p1[8] = make_float4(o1v[2][2], o1v[3][0], o1v[3][1], o1v[3][2]);
    }
    if (DO_Z && quad < 2) {
        int n = dst[me];
        float4 q0v = *(const float4*)&q0[(size_t)n * 8 + quad * 4];
        const float4* q1p = (const float4*)&q1[(size_t)n * 24 + quad * 12];
        float4 qa4 = q1p[0], qb4 = q1p[1], qc4 = q1p[2];
        float q1f[12] = {qa4.x, qa4.y, qa4.z, qa4.w, qb4.x, qb4.y, qb4.z, qb4.w,
                         qc4.x, qc4.y, qc4.z, qc4.w};
        float q0f[4] = {q0v.x, q0v.y, q0v.z, q0v.w};
        float zh0 = 0.f, zh1 = 0.f;
#pragma unroll
        for (int r = 0; r < 4; ++r) {
            float tt = q0f[r] * o0v[r] + q1f[r * 3 + 0] * o1v[r][0] +
                       q1f[r * 3 + 1] * o1v[r][1] + q1f[r * 3 + 2] * o1v[r][2];
            if (r < 2) zh0 += tt;
            else zh1 += tt;
        }
        const float scale = 0.35355339059327373f;  // 1/sqrt(8)
        *(float2*)&zb[(size_t)pos * 4 + quad * 2] = make_float2(zh0 * scale, zh1 * scale);
    }
}

// ---------------- per-node: softmax + aggregate + proj + SE3-norm (+next q) --
// 32 lanes per node, 2 nodes/wave, 8 nodes/block (2x waves vs r12).
__global__ __launch_bounds__(256) void k_attn(
    int N,
    const int* __restrict__ rowptr,
    const float* __restrict__ zb, const float* __restrict__ vrow,
    const float* __restrict__ wproj,  // (2,24,16)
    const float* __restrict__ gamma, const float* __restrict__ beta,  // (2,16)
    const float* __restrict__ xr0, const float* __restrict__ xr1,
    float* __restrict__ xs0, float* __restrict__ xs1,
    const float* __restrict__ wq_next,  // next layer wq (2,16,8) or nullptr
    float* __restrict__ q0, float* __restrict__ q1) {
    __shared__ float wpL[768];
    __shared__ float gL[32], btL[32];
    __shared__ float inb[8][100];   // per node: in0[24] + in1[72]
    __shared__ float aw[8][32][4];  // per node: alpha chunk (unnormalized)
    int tid = threadIdx.x;
    for (int i = tid; i < 768; i += 256) wpL[i] = wproj[i];
    if (tid < 32) { gL[tid] = gamma[tid]; btL[tid] = beta[tid]; }
    int wave = tid >> 6, lane = tid & 63;
    int sub = lane >> 5, l32 = lane & 31;
    int nodeIdx = wave * 2 + sub;
    int n = blockIdx.x * 8 + nodeIdx;
    if (n >= N) n = N - 1;
    int base = rowptr[n], deg = rowptr[n + 1] - base;
    const float4* zb4 = (const float4*)zb;

    // pass 1: per-head max (coalesced, 32-wide)
    float mx0 = -INFINITY, mx1 = -INFINITY, mx2 = -INFINITY, mx3 = -INFINITY;
    for (int j = l32; j < deg; j += 32) {
        float4 zv = zb4[base + j];
        mx0 = fmaxf(mx0, zv.x); mx1 = fmaxf(mx1, zv.y);
        mx2 = fmaxf(mx2, zv.z); mx3 = fmaxf(mx3, zv.w);
    }
#pragma unroll
    for (int off = 1; off < 32; off <<= 1) {
        mx0 = fmaxf(mx0, __shfl_xor(mx0, off));
        mx1 = fmaxf(mx1, __shfl_xor(mx1, off));
        mx2 = fmaxf(mx2, __shfl_xor(mx2, off));
        mx3 = fmaxf(mx3, __shfl_xor(mx3, off));
    }
    if (!isfinite(mx0)) mx0 = 0.f;
    if (!isfinite(mx1)) mx1 = 0.f;
    if (!isfinite(mx2)) mx2 = 0.f;
    if (!isfinite(mx3)) mx3 = 0.f;

    // pass 2 (merged): unnormalized alpha chunks of 32 -> LDS; lane owns comp c
    int c = l32;
    int hC = (c < 8) ? (c >> 1) : (((c - 8) / 3) >> 1);
    float s0 = 0.f, s1 = 0.f, s2 = 0.f, s3 = 0.f;
    float acc = 0.f;
    for (int j0 = 0; j0 < deg; j0 += 32) {
        int j = j0 + l32;
        float4 a4 = make_float4(0.f, 0.f, 0.f, 0.f);
        if (j < deg) {
            float4 zv = zb4[base + j];
            a4.x = __expf(zv.x - mx0);
            a4.y = __expf(zv.y - mx1);
            a4.z = __expf(zv.z - mx2);
            a4.w = __expf(zv.w - mx3);
            s0 += a4.x; s1 += a4.y; s2 += a4.z; s3 += a4.w;
        }
        *(float4*)&aw[nodeIdx][l32][0] = a4;
        __builtin_amdgcn_wave_barrier();
        int cnt = min(32, deg - j0);
        const float* vbase = &vrow[(size_t)(base + j0) * 32 + c];
        int jj = 0;
        for (; jj + 3 < cnt; jj += 4) {
            float v0 = vbase[(size_t)jj * 32];
            float v1 = vbase[(size_t)(jj + 1) * 32];
            float v2 = vbase[(size_t)(jj + 2) * 32];
            float v3 = vbase[(size_t)(jj + 3) * 32];
            acc += aw[nodeIdx][jj][hC] * v0 + aw[nodeIdx][jj + 1][hC] * v1 +
                   aw[nodeIdx][jj + 2][hC] * v2 + aw[nodeIdx][jj + 3][hC] * v3;
        }
        for (; jj < cnt; ++jj) acc += aw[nodeIdx][jj][hC] * vbase[(size_t)jj * 32];
        __builtin_amdgcn_wave_barrier();
    }
#pragma unroll
    for (int off = 1; off < 32; off <<= 1) {
        s0 += __shfl_xor(s0, off); s1 += __shfl_xor(s1, off);
        s2 += __shfl_xor(s2, off); s3 += __shfl_xor(s3, off);
    }
    float inva[4] = {1.f / (s0 + 1e-9f), 1.f / (s1 + 1e-9f),
                     1.f / (s2 + 1e-9f), 1.f / (s3 + 1e-9f)};
    acc *= inva[hC];

    // stage concat([o, x]) into LDS
    float* in0 = inb[nodeIdx];
    float* in1 = in0 + 24;
    if (c < 8) in0[c] = acc;
    else in1[c - 8] = acc;
    if (l32 < 16) {
        in0[8 + l32] = xr0[(size_t)n * 16 + l32];
        const float* xp = xr1 + (size_t)n * 48 + l32 * 3;
        in1[24 + l32 * 3 + 0] = xp[0];
        in1[24 + l32 * 3 + 1] = xp[1];
        in1[24 + l32 * 3 + 2] = xp[2];
    }
    __syncthreads();

    // projection + SE3 norm: lanes 0-15 of each node group, channel = l32
    if (l32 < 16) {
        int ch = l32;
        float y0 = 0.f;
#pragma unroll
        for (int j = 0; j < 24; ++j) y0 += in0[j] * wpL[j * 16 + ch];
        float y1v[3];
#pragma unroll
        for (int mm = 0; mm < 3; ++mm) {
            float y = 0.f;
#pragma unroll
            for (int j = 0; j < 24; ++j) y += in1[j * 3 + mm] * wpL[384 + j * 16 + ch];
            y1v[mm] = y;
        }
        float n0 = sqrtf(y0 * y0 + 1e-12f);
        float n1 = sqrtf(y1v[0] * y1v[0] + y1v[1] * y1v[1] + y1v[2] * y1v[2] + 1e-12f);
        float mu0 = n0, mu1 = n1;
#pragma unroll
        for (int off = 1; off < 16; off <<= 1) {
            mu0 += __shfl_xor(mu0, off);
            mu1 += __shfl_xor(mu1, off);
        }
        mu0 *= 0.0625f; mu1 *= 0.0625f;
        float dv0 = n0 - mu0, dv1 = n1 - mu1;
        float var0 = dv0 * dv0, var1 = dv1 * dv1;
#pragma unroll
        for (int off = 1; off < 16; off <<= 1) {
            var0 += __shfl_xor(var0, off);
            var1 += __shfl_xor(var1, off);
        }
        var0 *= 0.0625f; var1 *= 0.0625f;
        float ln0 = dv0 * rsqrtf(var0 + 1e-5f) * gL[ch] + btL[ch];
        float ln1 = dv1 * rsqrtf(var1 + 1e-5f) * gL[16 + ch] + btL[16 + ch];
        float fac0 = fmaxf(ln0, 0.f) / (n0 + 1e-3f);
        float fac1 = fmaxf(ln1, 0.f) / (n1 + 1e-3f);
        float x0n = y0 * fac0;
        float x1n[3] = {y1v[0] * fac1, y1v[1] * fac1, y1v[2] * fac1};
        xs0[(size_t)n * 16 + ch] = x0n;
        float* xo = xs1 + (size_t)n * 48 + ch * 3;
        xo[0] = x1n[0]; xo[1] = x1n[1]; xo[2] = x1n[2];

        // ---- fused next-layer q ----
        if (wq_next) {
            __builtin_amdgcn_wave_barrier();
            in0[8 + ch] = x0n;
            in1[24 + ch * 3 + 0] = x1n[0];
            in1[24 + ch * 3 + 1] = x1n[1];
            in1[24 + ch * 3 + 2] = x1n[2];
            __builtin_amdgcn_wave_barrier();
            int compA = 2 * ch, compB = compA + 1;
#pragma unroll
            for (int cb = 0; cb < 2; ++cb) {
                int comp = cb ? compB : compA;
                float a = 0.f;
                if (comp < 8) {
#pragma unroll
                    for (int cc = 0; cc < 16; ++cc)
                        a += in0[8 + cc] * wq_next[cc * 8 + comp];
                    q0[(size_t)n * 8 + comp] = a;
                } else {
                    int idx = comp - 8, dd = idx / 3, mm = idx % 3;
#pragma unroll
                    for (int cc = 0; cc < 16; ++cc)
                        a += in1[24 + cc * 3 + mm] * wq_next[128 + cc * 8 + dd];
                    q1[(size_t)n * 24 + idx] = a;
                }
            }
        }
    }
}

// ---------------- final output: segment-sum(vrow) + x @ wself ----------------
// 32 lanes per node, 2 nodes/wave, 8 nodes/block.
__global__ __launch_bounds__(256) void k_out(
    int N,
    const int* __restrict__ rowptr, const float* __restrict__ vrow,
    const float* __restrict__ xs0, const float* __restrict__ xs1,
    const float* __restrict__ wself,  // (2,16,8)
    float* __restrict__ out) {
    int tid = threadIdx.x;
    int wave = tid >> 6, lane = tid & 63;
    int sub = lane >> 5, l32 = lane & 31;
    int n = blockIdx.x * 8 + wave * 2 + sub;
    if (n >= N) n = N - 1;
    int base = rowptr[n], deg = rowptr[n + 1] - base;

    int c = l32;
    float acc = 0.f;
    const float* vbase = &vrow[(size_t)base * 32 + c];
    int j = 0;
    for (; j + 3 < deg; j += 4) {
        float v0 = vbase[(size_t)j * 32];
        float v1 = vbase[(size_t)(j + 1) * 32];
        float v2 = vbase[(size_t)(j + 2) * 32];
        float v3 = vbase[(size_t)(j + 3) * 32];
        acc += v0 + v1 + v2 + v3;
    }
    for (; j < deg; ++j) acc += vbase[(size_t)j * 32];
    if (c < 8) {
#pragma unroll
        for (int cc = 0; cc < 16; ++cc)
            acc += xs0[(size_t)n * 16 + cc] * wself[cc * 8 + c];
    } else {
        int dd = (c - 8) / 3, mm = (c - 8) % 3;
#pragma unroll
        for (int cc = 0; cc < 16; ++cc)
            acc += xs1[(size_t)n * 48 + cc * 3 + mm] * wself[128 + cc * 8 + dd];
    }
    out[(size_t)n * 32 + c] = acc;
}

// ---------------------------------------------------------------------------
extern "C" void kernel_launch(void* const* d_in, const int* in_sizes, int n_in,
                              void* d_out, int out_size, void* d_ws, size_t ws_size,
                              hipStream_t stream) {
    const float* x0 = (const float*)d_in[0];
    const float* x1 = (const float*)d_in[1];
    const float* ef = (const float*)d_in[2];
    const float* b00 = (const float*)d_in[3];
    const float* b01 = (const float*)d_in[4];
    const float* b10 = (const float*)d_in[5];
    const float* b11 = (const float*)d_in[6];
    const float* kvw1 = (const float*)d_in[7];    // (2,4,16,16)
    const float* kvw2n = (const float*)d_in[8];   // (2,3,16,16,16)
    const float* kvw211 = (const float*)d_in[9];  // (2,16,16,16,3)
    const float* wq = (const float*)d_in[10];     // (2,2,16,8)
    const float* wproj = (const float*)d_in[11];  // (2,2,24,16)
    const float* gam = (const float*)d_in[12];    // (2,2,16)
    const float* bet = (const float*)d_in[13];
    const float* fcw1 = (const float*)d_in[14];    // (4,16,16)
    const float* fcw2n = (const float*)d_in[15];   // (3,16,8,16)
    const float* fcw211 = (const float*)d_in[16];  // (16,8,16,3)
    const float* fcself = (const float*)d_in[17];  // (2,16,8)
    const int* esrc = (const int*)d_in[18];
    const int* edst = (const int*)d_in[19];
    int N = in_sizes[0] / 16;
    int E = in_sizes[18];
    float* out = (float*)d_out;

    float* ws = (float*)d_ws;
    size_t off = 0;
    float* xs0 = ws + off; off += (size_t)N * 16;
    float* xs1 = ws + off; off += (size_t)N * 48;
    float* q0b = ws + off; off += (size_t)N * 8;
    float* q1b = ws + off; off += (size_t)N * 24;
    float* vrow = ws + off; off += (size_t)E * 32;
    float* zb = ws + off; off += (size_t)E * 4;
    int* counts = (int*)(ws + off); off += N;
    int* rowptr = (int*)(ws + off); off += N + 1;
    int* cursor = (int*)(ws + off); off += N;
    int* pose = (int*)(ws + off); off += E;
    off = (off + 3) & ~(size_t)3;
    unsigned short* efh = (unsigned short*)(ws + off); off += (size_t)E * 16 / 2;
    unsigned short* b11h = (unsigned short*)(ws + off); off += (size_t)E * 28 / 2;
    unsigned short* Wfrag = (unsigned short*)(ws + off); off += (size_t)156 * 64 * 8 / 2;

    const int tpb = 256;
    int ebl = (E + 255) / 256;
    int cblk = (E / 16 + 3) / 4;
    int nbl8 = (N + 7) / 8;

    int itot = 156 * 512 + E * 16 + N * 32 + E * 27;
    k_init<<<(itot + 255) / 256, tpb, 0, stream>>>(x0, x1, ef, b11, kvw1, fcw1, kvw2n,
                                                   kvw211, fcw2n, fcw211, wq, efh,
                                                   Wfrag, q0b, q1b, b11h, N, E);
    hipMemsetAsync(counts, 0, (size_t)N * 4, stream);
    k_hist<<<ebl, tpb, 0, stream>>>(edst, counts, E);
    int CH = (N + 1023) / 1024;
    k_scan<<<1, 1024, 0, stream>>>(counts, rowptr, cursor, N, CH);
    k_scatter<<<ebl, tpb, 0, stream>>>(edst, cursor, pose, E);

    // layer 0 (reads x inputs directly; attn writes xs)
    k_conv<16, true><<<cblk, tpb, 0, stream>>>(E, esrc, edst, pose, x0, x1,
                                               b00, b01, b10, b11h, efh, Wfrag, 0,
                                               q0b, q1b, vrow, zb);
    k_attn<<<nbl8, tpb, 0, stream>>>(N, rowptr, zb, vrow, wproj, gam, bet,
                                     x0, x1, xs0, xs1, wq + 256, q0b, q1b);
    // layer 1
    k_conv<16, true><<<cblk, tpb, 0, stream>>>(E, esrc, edst, pose, xs0, xs1,
                                               b00, b01, b10, b11h, efh, Wfrag, 52,
                                               q0b, q1b, vrow, zb);
    k_attn<<<nbl8, tpb, 0, stream>>>(N, rowptr, zb, vrow, wproj + 768, gam + 32,
                                     bet + 32, xs0, xs1, xs0, xs1, nullptr, q0b, q1b);
    // final conv + output
    k_conv<8, false><<<cblk, tpb, 0, stream>>>(E, esrc, edst, pose, xs0, xs1,
                                               b00, b01, b10, b11h, efh, Wfrag, 104,
                                               q0b, q1b, vrow, zb);
    k_out<<<nbl8, tpb, 0, stream>>>(N, rowptr, vrow, xs0, xs1, fcself, out);
}